// Round 20
// baseline (392.250 us; speedup 1.0000x reference)
//
#include <hip/hip_runtime.h>
#include <cstdint>
#include <cmath>

#define BATCH 64

typedef __attribute__((ext_vector_type(8))) __bf16 bf16x8;
typedef __attribute__((ext_vector_type(16))) float f32x16;

// ---------------------------------------------------------------------------
// Spline + silu expansion: x -> [silu(x), B_0(x) .. B_7(x)]
// ---------------------------------------------------------------------------
__device__ __forceinline__ void expand9(float x, float* e) {
  float t = __expf(-x);
  e[0] = __fdividef(x, 1.f + t);  // silu
  float b[11];
#pragma unroll
  for (int j = 0; j < 11; ++j) {
    float gj  = 0.4f * (float)j - 2.2f;
    float gj1 = 0.4f * (float)(j + 1) - 2.2f;
    b[j] = (x >= gj && x < gj1) ? 1.f : 0.f;
  }
#pragma unroll
  for (int k = 1; k <= 3; ++k) {
    float inv = 1.f / (0.4f * (float)k);
#pragma unroll
    for (int j = 0; j < 11 - k; ++j) {
      float gj   = 0.4f * (float)j - 2.2f;
      float gjk1 = 0.4f * (float)(j + k + 1) - 2.2f;
      b[j] = ((x - gj) * b[j] + (gjk1 - x) * b[j + 1]) * inv;
    }
  }
#pragma unroll
  for (int v = 0; v < 8; ++v) e[v + 1] = b[v];
}

// bf16 split helpers (round-to-nearest-even)
__device__ __forceinline__ unsigned short f2bf(float x) {
  uint32_t u = __float_as_uint(x);
  uint32_t r = u + 0x7fffu + ((u >> 16) & 1u);
  return (unsigned short)(r >> 16);
}
__device__ __forceinline__ float bf2f(unsigned short h) {
  return __uint_as_float(((uint32_t)h) << 16);
}
__device__ __forceinline__ uint32_t packsplit(float x) {
  unsigned short hi = f2bf(x);
  unsigned short lo = f2bf(x - bf2f(hi));
  return (uint32_t)hi | ((uint32_t)lo << 16);
}

// ---------------------------------------------------------------------------
// h = relu(x @ lin_w^T + lin_b); also writes packed expansion E (12-stride).
// ---------------------------------------------------------------------------
__global__ __launch_bounds__(256) void linear_pack_kernel(
    const float* __restrict__ x, const float* __restrict__ w,
    const float* __restrict__ bias, float* __restrict__ h,
    uint32_t* __restrict__ E, int writeE) {
  int idx = blockIdx.x * 256 + threadIdx.x;  // 64*2048
  int b = idx >> 11, o = idx & 2047;
  const float* xr = x + b * 100;
  const float* wr = w + o * 100;
  float acc = bias[o];
#pragma unroll 4
  for (int k = 0; k < 100; ++k) acc += xr[k] * wr[k];
  float hv = fmaxf(acc, 0.f);
  h[idx] = hv;
  if (writeE) {
    float e[9];
    expand9(hv, e);
    uint32_t u0 = packsplit(e[0]), u1 = packsplit(e[1]), u2 = packsplit(e[2]);
    uint32_t u3 = packsplit(e[3]), u4 = packsplit(e[4]), u5 = packsplit(e[5]);
    uint32_t u6 = packsplit(e[6]), u7 = packsplit(e[7]), u8 = packsplit(e[8]);
    uint4* p = reinterpret_cast<uint4*>(E + (size_t)idx * 12);
    p[0] = make_uint4(u0, u1, u2, u3);
    p[1] = make_uint4(u4, u5, u6, u7);
    p[2] = make_uint4(u8, 0u, 0u, 0u);
  }
}

// ---------------------------------------------------------------------------
// Pack expanded weights (bf16-hi ONLY) into MFMA layout:
// Bg[kc][v(9)][n(N)][fl(16)]  (bf16)
// ---------------------------------------------------------------------------
template <int F, int N>
__global__ __launch_bounds__(256) void prep_bpack(
    const float* __restrict__ bw, const float* __restrict__ sw,
    const float* __restrict__ ss, unsigned short* __restrict__ Bg) {
  int idx = blockIdx.x * 256 + threadIdx.x;  // over (F/16)*9*N*16
  int fl = idx & 15;
  int n = (idx >> 4) & (N - 1);
  int rest = idx >> 4;
  rest /= N;
  int v = rest % 9;
  int kc = rest / 9;
  int f = kc * 16 + fl;
  size_t src = (size_t)n * F + f;
  float wv = (v == 0) ? bw[src] : sw[src * 8 + (v - 1)] * ss[src];
  Bg[((size_t)kc * 9 + v) * N * 16 + (size_t)n * 16 + fl] = f2bf(wv);
}

// ---------------------------------------------------------------------------
// bf16 MFMA GEMM — round-17/19 proven body. Round-20 change (ONLY): SK x1.5
// -> 1536 blocks = 6 blocks/CU (CPB=12 for all layers).
// ---------------------------------------------------------------------------
template <int CIN, int COUT, int HO, int WO, int SK>
__global__ __launch_bounds__(256, 4) void gemm_mfma(
    const uint32_t* __restrict__ E, const unsigned short* __restrict__ Bg,
    float* __restrict__ part) {
  constexpr int F = CIN * 9;
  constexpr int NKC = F / 16;
  constexpr int HI = HO / 2, WI = WO / 2;
  constexpr int M = BATCH * HO * WO;
  constexpr int CPB = NKC / SK;
  static_assert(NKC % SK == 0, "sk");

  // plane 0: A-hi [9][64][16]; plane 1: B-hi
  __shared__ __align__(16) unsigned short lds[2 * 9216];

  const int t = threadIdx.x;
  const int mbase = blockIdx.x * 64;
  const int nb = blockIdx.y;
  const int kc0 = blockIdx.z * CPB;

  uint32_t ez[9];
  {
    float e0[9];
    expand9(0.f, e0);
#pragma unroll
    for (int v = 0; v < 9; ++v) ez[v] = packsplit(e0[v]);
  }

  const int lane = t & 63, wv_ = t >> 6;
  const int wm = wv_ >> 1, wn = wv_ & 1;
  const int frow = lane & 31, fkg = lane >> 5;
  const int aoff = ((wm * 32 + frow) * 16 + fkg * 8) * 2;  // bytes
  const int boff = ((wn * 32 + frow) * 16 + fkg * 8) * 2;

  // A-staging geometry: thread covers row aml, fl = flq*4..+3
  const int aml = t >> 2, flq = t & 3;
  const int am = mbase + aml;
  const int ab = am / (HO * WO), ahw = am % (HO * WO);
  const int ahh = ahw / WO, aww = ahw % WO;

  f32x16 acc;
#pragma unroll
  for (int i = 0; i < 16; ++i) acc[i] = 0.f;

  for (int ci = 0; ci < CPB; ++ci) {
    const int kc = kc0 + ci;
    __syncthreads();

    // ---- stage A (hi only): 4 taps/thread, 3 dwordx4 loads per tap ----
    {
      uint32_t w0[9], w1[9], w2[9], w3[9];
#define LDTAP(IDX, DST)                                                       \
  {                                                                           \
    int f = kc * 16 + flq * 4 + IDX;                                          \
    int c = f / 9, r = f - 9 * c;                                             \
    int kh = r / 3, kw = r - kh * 3;                                          \
    int hp = ahh + kh - 1, wp = aww + kw - 1;                                 \
    if ((unsigned)hp < (unsigned)HO && (unsigned)wp < (unsigned)WO) {         \
      const uint4* ep4 = reinterpret_cast<const uint4*>(                      \
          E + (size_t)(((ab * CIN + c) * HI + (hp >> 1)) * WI + (wp >> 1)) *  \
                  12);                                                        \
      uint4 q0 = ep4[0], q1 = ep4[1], q2 = ep4[2];                            \
      DST[0] = q0.x; DST[1] = q0.y; DST[2] = q0.z; DST[3] = q0.w;             \
      DST[4] = q1.x; DST[5] = q1.y; DST[6] = q1.z; DST[7] = q1.w;             \
      DST[8] = q2.x;                                                          \
    } else {                                                                  \
      _Pragma("unroll") for (int v = 0; v < 9; ++v) DST[v] = ez[v];           \
    }                                                                         \
  }
      LDTAP(0, w0)
      LDTAP(1, w1)
      LDTAP(2, w2)
      LDTAP(3, w3)
#undef LDTAP
      char* lb = reinterpret_cast<char*>(lds);
#pragma unroll
      for (int v = 0; v < 9; ++v) {
        uint32_t hi01 = (w0[v] & 0xffffu) | (w1[v] << 16);
        uint32_t hi23 = (w2[v] & 0xffffu) | (w3[v] << 16);
        *reinterpret_cast<uint2*>(lb + v * 2048 + aml * 32 + flq * 8) =
            make_uint2(hi01, hi23);
      }
    }

    // ---- stage B: one plane, 1152 float4s over 256 threads ----
    {
      const unsigned short* bsrc = Bg + (size_t)kc * (9 * COUT * 16);
#define STAGEB(U)                                                             \
  {                                                                           \
    int u = (U);                                                              \
    int v = u >> 7, q = u & 127;                                              \
    int nl = q >> 1, half = q & 1;                                            \
    size_t srcE = (size_t)v * (COUT * 16) + (size_t)(nb * 64 + nl) * 16 +     \
                  half * 8;                                                   \
    int dst = 9216 + v * 1024 + nl * 16 + half * 8;                           \
    *reinterpret_cast<float4*>(&lds[dst]) =                                   \
        *reinterpret_cast<const float4*>(&bsrc[srcE]);                        \
  }
      STAGEB(t)
      STAGEB(256 + t)
      STAGEB(512 + t)
      STAGEB(768 + t)
      if (t < 128) STAGEB(1024 + t)
#undef STAGEB
    }
    __syncthreads();

    // ---- compute: 9 v-steps x 1 product ----
#pragma unroll
    for (int v = 0; v < 9; ++v) {
      const char* lbc = reinterpret_cast<const char*>(lds);
      bf16x8 ah = *reinterpret_cast<const bf16x8*>(lbc + v * 2048 + aoff);
      bf16x8 bh =
          *reinterpret_cast<const bf16x8*>(lbc + 18432 + v * 2048 + boff);
      acc = __builtin_amdgcn_mfma_f32_32x32x16_bf16(ah, bh, acc, 0, 0, 0);
    }
  }

  // ---- epilogue: C/D layout col=lane&31, row=(reg&3)+8*(reg>>2)+4*(lane>>5)
  float* p = part + (size_t)blockIdx.z * M * COUT;
  const int gn = nb * 64 + wn * 32 + frow;
#pragma unroll
  for (int r = 0; r < 16; ++r) {
    int mlocal = (r & 3) + 8 * (r >> 2) + 4 * fkg;
    int gm = mbase + wm * 32 + mlocal;
    p[(size_t)gm * COUT + gn] = acc[r];
  }
}

// ---------------------------------------------------------------------------
// Reduce split-K partials -> activation; write packed 12-stride expansion E.
// ---------------------------------------------------------------------------
template <int COUT, int HO, int WO>
__global__ __launch_bounds__(256) void reduce_pe_pack(
    const float* __restrict__ part, uint32_t* __restrict__ E, int SK) {
  constexpr int M = BATCH * HO * WO;
  int idx = blockIdx.x * 256 + threadIdx.x;
  int ww = idx % WO;
  int tmp = idx / WO;
  int hh = tmp % HO;
  tmp /= HO;
  int o = tmp % COUT;
  int b = tmp / COUT;
  int m = (b * HO + hh) * WO + ww;
  float s = 0.f;
  for (int k = 0; k < SK; ++k) s += part[((size_t)k * M + m) * COUT + o];
  float e[9];
  expand9(s, e);
  uint32_t u0 = packsplit(e[0]), u1 = packsplit(e[1]), u2 = packsplit(e[2]);
  uint32_t u3 = packsplit(e[3]), u4 = packsplit(e[4]), u5 = packsplit(e[5]);
  uint32_t u6 = packsplit(e[6]), u7 = packsplit(e[7]), u8 = packsplit(e[8]);
  uint4* p = reinterpret_cast<uint4*>(E + (size_t)idx * 12);
  p[0] = make_uint4(u0, u1, u2, u3);
  p[1] = make_uint4(u4, u5, u6, u7);
  p[2] = make_uint4(u8, 0u, 0u, 0u);
}

template <int COUT, int HO, int WO>
__global__ __launch_bounds__(256) void reduce_p(
    const float* __restrict__ part, float* __restrict__ act, int SK) {
  constexpr int M = BATCH * HO * WO;
  int idx = blockIdx.x * 256 + threadIdx.x;
  int ww = idx % WO;
  int tmp = idx / WO;
  int hh = tmp % HO;
  tmp /= HO;
  int o = tmp % COUT;
  int b = tmp / COUT;
  int m = (b * HO + hh) * WO + ww;
  float s = 0.f;
  for (int k = 0; k < SK; ++k) s += part[((size_t)k * M + m) * COUT + o];
  act[idx] = s;
}

// ---------------------------------------------------------------------------
// L4 weights, neighbor-pre-summed:
// Wn[c][pc][nb][v][o] = sum over taps mapping to neighbor nb under parity pc.
// ---------------------------------------------------------------------------
__global__ __launch_bounds__(256) void prep_wnl4(
    const float* __restrict__ bw, const float* __restrict__ sw,
    const float* __restrict__ ss, float* __restrict__ Wn) {
  int idx = blockIdx.x * 256 + threadIdx.x;  // 64*4*4*27 = 27648
  if (idx >= 27648) return;
  int u = idx % 27;
  int o = u % 3, v = u / 3;
  int rest = idx / 27;
  int nb = rest & 3;
  rest >>= 2;
  int pc = rest & 3;
  rest >>= 2;
  int c = rest;  // 0..63
  int PH = pc >> 1, PW = pc & 1;
  int a = nb >> 1, b2 = nb & 1;
  float s = 0.f;
#pragma unroll
  for (int kh = 0; kh < 3; ++kh) {
    if (((kh > PH) ? 1 : 0) != a) continue;
#pragma unroll
    for (int kw = 0; kw < 3; ++kw) {
      if (((kw > PW) ? 1 : 0) != b2) continue;
      int f = c * 9 + kh * 3 + kw;
      float wv = (v == 0)
                     ? bw[o * 576 + f]
                     : sw[((size_t)(o * 576 + f)) * 8 + (v - 1)] * ss[o * 576 + f];
      s += wv;
    }
  }
  Wn[idx] = s;
}

// ---------------------------------------------------------------------------
// L4 v8: round-10 proven skeleton, channel-split 16 -> 32 groups
// (2 channels/block, 2048 blocks = 8 blocks/CU, LDS 18.4KB).
// ---------------------------------------------------------------------------
template <int PH, int PW>
__device__ void l4v8_wave(const float* __restrict__ eLds,
                          const float* __restrict__ WnB,
                          const float* __restrict__ ez, int lane, int bb,
                          int cs, float* __restrict__ p4) {
  constexpr int PC = PH * 2 + PW;
  const int j = lane & 15;
  const int i0 = (lane >> 4) << 2;
#pragma unroll 1
  for (int q = 0; q < 4; ++q) {
    const int i = i0 + q;
    float acc[3] = {0.f, 0.f, 0.f};
#pragma unroll
    for (int a = 0; a < 2; ++a) {
      const int gi = i + PH - 1 + a;
      const bool vr = (unsigned)gi < 16u;
#pragma unroll
      for (int b2 = 0; b2 < 2; ++b2) {
        const int gj = j + PW - 1 + b2;
        const bool ok = vr && ((unsigned)gj < 16u);
        const int pp = ok ? (gi * 16 + gj) : 0;  // clamped safe address
        const int nbi = a * 2 + b2;
#pragma unroll
        for (int cl = 0; cl < 2; ++cl) {
          const float* ep = eLds + cl * 2304 + pp * 9;
          float en[9];
#pragma unroll
          for (int v = 0; v < 9; ++v) en[v] = ok ? ep[v] : ez[v];
          const float* wp = WnB + ((cl * 4 + PC) * 4 + nbi) * 27;
#pragma unroll
          for (int v = 0; v < 9; ++v) {
            acc[0] = fmaf(en[v], wp[v * 3 + 0], acc[0]);
            acc[1] = fmaf(en[v], wp[v * 3 + 1], acc[1]);
            acc[2] = fmaf(en[v], wp[v * 3 + 2], acc[2]);
          }
        }
      }
    }
    const int h = (i << 1) + PH, w = (j << 1) + PW;
#pragma unroll
    for (int o = 0; o < 3; ++o)
      p4[(size_t)cs * 196608 + ((bb * 3 + o) << 10) + (h << 5) + w] = acc[o];
  }
}

__global__ __launch_bounds__(256) void kan_l4_v8(
    const float* __restrict__ a3, const float* __restrict__ Wn,
    float* __restrict__ p4) {
  __shared__ float eLds[2 * 256 * 9];  // 18.4 KB
  const int bid = blockIdx.x;          // 64 bb x 32 cs
  const int bb = bid >> 5, cs = bid & 31;
  const int t = threadIdx.x;
  float ez[9];
  expand9(0.f, ez);
#pragma unroll
  for (int cl = 0; cl < 2; ++cl) {
    float x = a3[(size_t)(bb * 64 + cs * 2 + cl) * 256 + t];
    float ev[9];
    expand9(x, ev);
#pragma unroll
    for (int v = 0; v < 9; ++v) eLds[(cl * 256 + t) * 9 + v] = ev[v];
  }
  __syncthreads();
  const int wv_ = t >> 6, lane = t & 63;
  const float* WnB = Wn + (size_t)cs * 2 * (4 * 4 * 27);
  if (wv_ == 0)
    l4v8_wave<0, 0>(eLds, WnB, ez, lane, bb, cs, p4);
  else if (wv_ == 1)
    l4v8_wave<0, 1>(eLds, WnB, ez, lane, bb, cs, p4);
  else if (wv_ == 2)
    l4v8_wave<1, 0>(eLds, WnB, ez, lane, bb, cs, p4);
  else
    l4v8_wave<1, 1>(eLds, WnB, ez, lane, bb, cs, p4);
}

__global__ __launch_bounds__(256) void reduce_tanh_l4_32(
    const float* __restrict__ p4, float* __restrict__ out) {
  int i = blockIdx.x * 256 + threadIdx.x;  // 196608
  float s = 0.f;
#pragma unroll
  for (int k = 0; k < 32; ++k) s += p4[(size_t)k * 196608 + i];
  out[i] = tanhf(s);
}

__global__ __launch_bounds__(256) void reduce_tanh_l4(
    const float* __restrict__ p4, float* __restrict__ out) {
  int i = blockIdx.x * 256 + threadIdx.x;
  float s = p4[i] + p4[i + 196608] + p4[i + 2 * 196608] + p4[i + 3 * 196608];
  out[i] = tanhf(s);
}

// ---------------------------------------------------------------------------
// Fallback path (round-1 proven) for small workspace
// ---------------------------------------------------------------------------
template <int CIN, int COUT, int HO, int WO, int BN, int SK>
__global__ __launch_bounds__(256) void kan_gemm(
    const float* __restrict__ in, const float* __restrict__ bw,
    const float* __restrict__ sw, const float* __restrict__ ss,
    float* __restrict__ outp) {
  constexpr int BM = 64, TM = 4, TN = 4, FC = 16;
  constexpr int F = CIN * 9;
  constexpr int HI = HO / 2, WI = WO / 2;
  constexpr int M = BATCH * HO * WO;
  constexpr int FPB = F / SK;

  __shared__ float Ae[FC * 9][BM];

  const int t = threadIdx.x;
  const int mbase = blockIdx.x * BM;
  const int obase = blockIdx.y * BN;
  const int f0 = blockIdx.z * FPB;

  const int cg = t & (BN / TN - 1);
  const int rg = t / (BN / TN);
  const int m0 = rg * TM;
  const int o0 = obase + cg * TN;

  float acc[TM][TN] = {};

  for (int fc = f0; fc < f0 + FPB; fc += FC) {
#pragma unroll
    for (int j = 0; j < BM * FC / 256; ++j) {
      int p = j * 256 + t;
      int ml = p & (BM - 1);
      int df = p >> 6;
      int f = fc + df;
      int c = f / 9;
      int r = f - c * 9;
      int kh = r / 3, kw = r - kh * 3;
      int m = mbase + ml;
      int bb = m / (HO * WO);
      int rem = m % (HO * WO);
      int hh = rem / WO, ww = rem % WO;
      int hp = hh + kh - 1, wp = ww + kw - 1;
      float val = 0.f;
      if (hp >= 0 && hp < HO && wp >= 0 && wp < WO)
        val = in[((bb * CIN + c) * HI + (hp >> 1)) * WI + (wp >> 1)];
      float e[9];
      expand9(val, e);
#pragma unroll
      for (int v = 0; v < 9; ++v) Ae[df * 9 + v][ml] = e[v];
    }
    __syncthreads();

#pragma unroll 2
    for (int df = 0; df < FC; ++df) {
      int f = fc + df;
      float wb[TN], wsv[TN][8];
#pragma unroll
      for (int tn = 0; tn < TN; ++tn) {
        int i = (o0 + tn) * F + f;
        wb[tn] = bw[i];
        float sc = ss[i];
        const float4* sp = reinterpret_cast<const float4*>(sw + (size_t)i * 8);
        float4 s0 = sp[0], s1 = sp[1];
        wsv[tn][0] = s0.x * sc; wsv[tn][1] = s0.y * sc;
        wsv[tn][2] = s0.z * sc; wsv[tn][3] = s0.w * sc;
        wsv[tn][4] = s1.x * sc; wsv[tn][5] = s1.y * sc;
        wsv[tn][6] = s1.z * sc; wsv[tn][7] = s1.w * sc;
      }
      float a[9][TM];
#pragma unroll
      for (int v = 0; v < 9; ++v) {
        float4 q = *reinterpret_cast<const float4*>(&Ae[df * 9 + v][m0]);
        a[v][0] = q.x; a[v][1] = q.y; a[v][2] = q.z; a[v][3] = q.w;
      }
#pragma unroll
      for (int tm = 0; tm < TM; ++tm)
#pragma unroll
        for (int tn = 0; tn < TN; ++tn) acc[tm][tn] += a[0][tm] * wb[tn];
#pragma unroll
      for (int v = 1; v < 9; ++v)
#pragma unroll
        for (int tm = 0; tm < TM; ++tm)
#pragma unroll
          for (int tn = 0; tn < TN; ++tn)
            acc[tm][tn] += a[v][tm] * wsv[tn][v - 1];
    }
    __syncthreads();
  }

  if constexpr (SK > 1) {
    float* p = outp + (size_t)blockIdx.z * M * COUT;
#pragma unroll
    for (int tm = 0; tm < TM; ++tm) {
      int m = mbase + m0 + tm;
#pragma unroll
      for (int tn = 0; tn < TN; ++tn)
        p[(size_t)m * COUT + (o0 + tn)] = acc[tm][tn];
    }
  } else {
#pragma unroll
    for (int tm = 0; tm < TM; ++tm) {
      int m = mbase + m0 + tm;
      int bb = m / (HO * WO);
      int rem = m % (HO * WO);
      int hh = rem / WO, ww = rem % WO;
#pragma unroll
      for (int tn = 0; tn < TN; ++tn) {
        int o = o0 + tn;
        outp[((bb * COUT + o) * HO + hh) * WO + ww] = acc[tm][tn];
      }
    }
  }
}

template <int COUT, int HO, int WO, int SK>
__global__ __launch_bounds__(256) void reduce_partials_old(
    const float* __restrict__ part, float* __restrict__ act) {
  constexpr int M = BATCH * HO * WO;
  int idx = blockIdx.x * 256 + threadIdx.x;
  if (idx >= M * COUT) return;
  float s = 0.f;
#pragma unroll
  for (int k = 0; k < SK; ++k) s += part[(size_t)k * M * COUT + idx];
  int m = idx / COUT, o = idx - (idx / COUT) * COUT;
  int bb = m / (HO * WO);
  int rem = m % (HO * WO);
  int hh = rem / WO, ww = rem % WO;
  act[((bb * COUT + o) * HO + hh) * WO + ww] = s;
}

__global__ __launch_bounds__(256) void kan_l4_split(
    const float* __restrict__ a3, const float* __restrict__ bw,
    const float* __restrict__ sw, const float* __restrict__ ss,
    float* __restrict__ p4) {
  int tid = blockIdx.x * 256 + threadIdx.x;
  int cs = tid >> 16, pix = tid & 65535;
  int b = pix >> 10, rem = pix & 1023, h = rem >> 5, w = rem & 31;
  float acc[3] = {0.f, 0.f, 0.f};
  for (int c = cs * 16; c < cs * 16 + 16; ++c) {
#pragma unroll
    for (int kh = 0; kh < 3; ++kh) {
#pragma unroll
      for (int kw = 0; kw < 3; ++kw) {
        int f = (c * 3 + kh) * 3 + kw;
        int hp = h + kh - 1, wp = w + kw - 1;
        float x = 0.f;
        if ((unsigned)hp < 32u && (unsigned)wp < 32u)
          x = a3[((b * 64 + c) * 16 + (hp >> 1)) * 16 + (wp >> 1)];
        float e[9];
        expand9(x, e);
#pragma unroll
        for (int o = 0; o < 3; ++o) {
          int i = o * 576 + f;
          float d = e[1] * sw[i * 8 + 0];
#pragma unroll
          for (int v = 1; v < 8; ++v) d += e[v + 1] * sw[i * 8 + v];
          acc[o] += e[0] * bw[i] + d * ss[i];
        }
      }
    }
  }
#pragma unroll
  for (int o = 0; o < 3; ++o)
    p4[cs * 196608 + ((b * 3 + o) << 10) + (h << 5) + w] = acc[o];
}

// ---------------------------------------------------------------------------
extern "C" void kernel_launch(void* const* d_in, const int* in_sizes, int n_in,
                              void* d_out, int out_size, void* d_ws,
                              size_t ws_size, hipStream_t stream) {
  const float* x     = (const float*)d_in[0];
  const float* lin_w = (const float*)d_in[1];
  const float* lin_b = (const float*)d_in[2];
  const float* bw1 = (const float*)d_in[3];
  const float* sw1 = (const float*)d_in[4];
  const float* ss1 = (const float*)d_in[5];
  const float* bw2 = (const float*)d_in[6];
  const float* sw2 = (const float*)d_in[7];
  const float* ss2 = (const float*)d_in[8];
  const float* bw3 = (const float*)d_in[9];
  const float* sw3 = (const float*)d_in[10];
  const float* ss3 = (const float*)d_in[11];
  const float* bw4 = (const float*)d_in[12];
  const float* sw4 = (const float*)d_in[13];
  const float* ss4 = (const float*)d_in[14];

  float* wsf = (float*)d_ws;
  // ---- main-path layout (round 20): total 19,070,976 floats = 76.3 MB ----
  float* h    = wsf;                                       // 131072 (wl4 alias)
  float* a3   = wsf + 131072;                              // 1048576
  unsigned short* Bg = (unsigned short*)(wsf + 1179648);   // 5,308,416 floats
  float* part = wsf + 6488064;                             // 6,291,456 (SK=24)
  uint32_t* Eg = (uint32_t*)(wsf + 12779520);              // 6,291,456 (12/pix)
  float* wl4 = h;
  float* p4  = wsf + 12779520;  // aliases Eg (dead post-L3), 32*196608 floats

  const size_t mainNeed = 19070976ull;

  if (ws_size / 4 >= mainNeed) {
    linear_pack_kernel<<<512, 256, 0, stream>>>(x, lin_w, lin_b, h, Eg, 1);

    // L1: CIN=512 COUT=256 4x4, SK=24 (1536 blocks, CPB=12)
    prep_bpack<4608, 256><<<41472, 256, 0, stream>>>(bw1, sw1, ss1, Bg);
    gemm_mfma<512, 256, 4, 4, 24>
        <<<dim3(16, 4, 24), 256, 0, stream>>>(Eg, Bg, part);
    reduce_pe_pack<256, 4, 4><<<1024, 256, 0, stream>>>(part, Eg, 24);

    // L2: CIN=256 COUT=128 8x8, SK=12 (1536 blocks, CPB=12)
    prep_bpack<2304, 128><<<10368, 256, 0, stream>>>(bw2, sw2, ss2, Bg);
    gemm_mfma<256, 128, 8, 8, 12>
        <<<dim3(64, 2, 12), 256, 0, stream>>>(Eg, Bg, part);
    reduce_pe_pack<128, 8, 8><<<2048, 256, 0, stream>>>(part, Eg, 12);

    // L3: CIN=128 COUT=64 16x16, SK=6 (1536 blocks, CPB=12)
    prep_bpack<1152, 64><<<2592, 256, 0, stream>>>(bw3, sw3, ss3, Bg);
    gemm_mfma<128, 64, 16, 16, 6>
        <<<dim3(256, 1, 6), 256, 0, stream>>>(Eg, Bg, part);
    reduce_p<64, 16, 16><<<4096, 256, 0, stream>>>(part, a3, 6);

    // L4: 32 channel groups (2 ch/block, 2048 blocks) + tanh reduce
    prep_wnl4<<<108, 256, 0, stream>>>(bw4, sw4, ss4, wl4);
    kan_l4_v8<<<2048, 256, 0, stream>>>(a3, wl4, p4);
    reduce_tanh_l4_32<<<768, 256, 0, stream>>>(p4, (float*)d_out);
  } else {
    // round-1 proven fallback (needs ~16.3 MB), original layout
    float* hF  = wsf;
    float* a1F = hF + 131072;
    float* a2F = a1F + 262144;
    float* a3F = a2F + 524288;
    float* partOld = a3F + 1048576;
    linear_pack_kernel<<<512, 256, 0, stream>>>(x, lin_w, lin_b, hF, nullptr, 0);
    kan_gemm<512, 256, 4, 4, 64, 8>
        <<<dim3(16, 4, 8), 256, 0, stream>>>(hF, bw1, sw1, ss1, partOld);
    reduce_partials_old<256, 4, 4, 8><<<1024, 256, 0, stream>>>(partOld, a1F);
    kan_gemm<256, 128, 8, 8, 64, 2>
        <<<dim3(64, 2, 2), 256, 0, stream>>>(a1F, bw2, sw2, ss2, partOld);
    reduce_partials_old<128, 8, 8, 2><<<2048, 256, 0, stream>>>(partOld, a2F);
    kan_gemm<128, 64, 16, 16, 64, 1>
        <<<dim3(256, 1, 1), 256, 0, stream>>>(a2F, bw3, sw3, ss3, a3F);
    kan_l4_split<<<1024, 256, 0, stream>>>(a3F, bw4, sw4, ss4, partOld);
    reduce_tanh_l4<<<768, 256, 0, stream>>>(partOld, (float*)d_out);
  }
}

// Round 21
// 350.406 us; speedup vs baseline: 1.1194x; 1.1194x over previous
//
#include <hip/hip_runtime.h>
#include <cstdint>
#include <cmath>

#define BATCH 64

typedef __attribute__((ext_vector_type(8))) __bf16 bf16x8;
typedef __attribute__((ext_vector_type(16))) float f32x16;

// ---------------------------------------------------------------------------
// Spline + silu expansion: x -> [silu(x), B_0(x) .. B_7(x)]
// ---------------------------------------------------------------------------
__device__ __forceinline__ void expand9(float x, float* e) {
  float t = __expf(-x);
  e[0] = __fdividef(x, 1.f + t);  // silu
  float b[11];
#pragma unroll
  for (int j = 0; j < 11; ++j) {
    float gj  = 0.4f * (float)j - 2.2f;
    float gj1 = 0.4f * (float)(j + 1) - 2.2f;
    b[j] = (x >= gj && x < gj1) ? 1.f : 0.f;
  }
#pragma unroll
  for (int k = 1; k <= 3; ++k) {
    float inv = 1.f / (0.4f * (float)k);
#pragma unroll
    for (int j = 0; j < 11 - k; ++j) {
      float gj   = 0.4f * (float)j - 2.2f;
      float gjk1 = 0.4f * (float)(j + k + 1) - 2.2f;
      b[j] = ((x - gj) * b[j] + (gjk1 - x) * b[j + 1]) * inv;
    }
  }
#pragma unroll
  for (int v = 0; v < 8; ++v) e[v + 1] = b[v];
}

// bf16 split helpers (round-to-nearest-even)
__device__ __forceinline__ unsigned short f2bf(float x) {
  uint32_t u = __float_as_uint(x);
  uint32_t r = u + 0x7fffu + ((u >> 16) & 1u);
  return (unsigned short)(r >> 16);
}
__device__ __forceinline__ float bf2f(unsigned short h) {
  return __uint_as_float(((uint32_t)h) << 16);
}
__device__ __forceinline__ uint32_t packsplit(float x) {
  unsigned short hi = f2bf(x);
  unsigned short lo = f2bf(x - bf2f(hi));
  return (uint32_t)hi | ((uint32_t)lo << 16);
}

// ---------------------------------------------------------------------------
// h = relu(x @ lin_w^T + lin_b); also writes packed expansion E (12-stride).
// ---------------------------------------------------------------------------
__global__ __launch_bounds__(256) void linear_pack_kernel(
    const float* __restrict__ x, const float* __restrict__ w,
    const float* __restrict__ bias, float* __restrict__ h,
    uint32_t* __restrict__ E, int writeE) {
  int idx = blockIdx.x * 256 + threadIdx.x;  // 64*2048
  int b = idx >> 11, o = idx & 2047;
  const float* xr = x + b * 100;
  const float* wr = w + o * 100;
  float acc = bias[o];
#pragma unroll 4
  for (int k = 0; k < 100; ++k) acc += xr[k] * wr[k];
  float hv = fmaxf(acc, 0.f);
  h[idx] = hv;
  if (writeE) {
    float e[9];
    expand9(hv, e);
    uint32_t u0 = packsplit(e[0]), u1 = packsplit(e[1]), u2 = packsplit(e[2]);
    uint32_t u3 = packsplit(e[3]), u4 = packsplit(e[4]), u5 = packsplit(e[5]);
    uint32_t u6 = packsplit(e[6]), u7 = packsplit(e[7]), u8 = packsplit(e[8]);
    uint4* p = reinterpret_cast<uint4*>(E + (size_t)idx * 12);
    p[0] = make_uint4(u0, u1, u2, u3);
    p[1] = make_uint4(u4, u5, u6, u7);
    p[2] = make_uint4(u8, 0u, 0u, 0u);
  }
}

// ---------------------------------------------------------------------------
// Pack expanded weights (bf16-hi ONLY) into MFMA layout:
// Bg[kc][v(9)][n(N)][fl(16)]  (bf16)
// ---------------------------------------------------------------------------
template <int F, int N>
__global__ __launch_bounds__(256) void prep_bpack(
    const float* __restrict__ bw, const float* __restrict__ sw,
    const float* __restrict__ ss, unsigned short* __restrict__ Bg) {
  int idx = blockIdx.x * 256 + threadIdx.x;  // over (F/16)*9*N*16
  int fl = idx & 15;
  int n = (idx >> 4) & (N - 1);
  int rest = idx >> 4;
  rest /= N;
  int v = rest % 9;
  int kc = rest / 9;
  int f = kc * 16 + fl;
  size_t src = (size_t)n * F + f;
  float wv = (v == 0) ? bw[src] : sw[src * 8 + (v - 1)] * ss[src];
  Bg[((size_t)kc * 9 + v) * N * 16 + (size_t)n * 16 + fl] = f2bf(wv);
}

// ---------------------------------------------------------------------------
// bf16 MFMA GEMM — round-19 proven config (SK=16/8/4, 1024 blocks, CPB=18).
// ---------------------------------------------------------------------------
template <int CIN, int COUT, int HO, int WO, int SK>
__global__ __launch_bounds__(256, 4) void gemm_mfma(
    const uint32_t* __restrict__ E, const unsigned short* __restrict__ Bg,
    float* __restrict__ part) {
  constexpr int F = CIN * 9;
  constexpr int NKC = F / 16;
  constexpr int HI = HO / 2, WI = WO / 2;
  constexpr int M = BATCH * HO * WO;
  constexpr int CPB = NKC / SK;
  static_assert(NKC % SK == 0, "sk");

  // plane 0: A-hi [9][64][16]; plane 1: B-hi
  __shared__ __align__(16) unsigned short lds[2 * 9216];

  const int t = threadIdx.x;
  const int mbase = blockIdx.x * 64;
  const int nb = blockIdx.y;
  const int kc0 = blockIdx.z * CPB;

  uint32_t ez[9];
  {
    float e0[9];
    expand9(0.f, e0);
#pragma unroll
    for (int v = 0; v < 9; ++v) ez[v] = packsplit(e0[v]);
  }

  const int lane = t & 63, wv_ = t >> 6;
  const int wm = wv_ >> 1, wn = wv_ & 1;
  const int frow = lane & 31, fkg = lane >> 5;
  const int aoff = ((wm * 32 + frow) * 16 + fkg * 8) * 2;  // bytes
  const int boff = ((wn * 32 + frow) * 16 + fkg * 8) * 2;

  // A-staging geometry: thread covers row aml, fl = flq*4..+3
  const int aml = t >> 2, flq = t & 3;
  const int am = mbase + aml;
  const int ab = am / (HO * WO), ahw = am % (HO * WO);
  const int ahh = ahw / WO, aww = ahw % WO;

  f32x16 acc;
#pragma unroll
  for (int i = 0; i < 16; ++i) acc[i] = 0.f;

  for (int ci = 0; ci < CPB; ++ci) {
    const int kc = kc0 + ci;
    __syncthreads();

    // ---- stage A (hi only): 4 taps/thread, 3 dwordx4 loads per tap ----
    {
      uint32_t w0[9], w1[9], w2[9], w3[9];
#define LDTAP(IDX, DST)                                                       \
  {                                                                           \
    int f = kc * 16 + flq * 4 + IDX;                                          \
    int c = f / 9, r = f - 9 * c;                                             \
    int kh = r / 3, kw = r - kh * 3;                                          \
    int hp = ahh + kh - 1, wp = aww + kw - 1;                                 \
    if ((unsigned)hp < (unsigned)HO && (unsigned)wp < (unsigned)WO) {         \
      const uint4* ep4 = reinterpret_cast<const uint4*>(                      \
          E + (size_t)(((ab * CIN + c) * HI + (hp >> 1)) * WI + (wp >> 1)) *  \
                  12);                                                        \
      uint4 q0 = ep4[0], q1 = ep4[1], q2 = ep4[2];                            \
      DST[0] = q0.x; DST[1] = q0.y; DST[2] = q0.z; DST[3] = q0.w;             \
      DST[4] = q1.x; DST[5] = q1.y; DST[6] = q1.z; DST[7] = q1.w;             \
      DST[8] = q2.x;                                                          \
    } else {                                                                  \
      _Pragma("unroll") for (int v = 0; v < 9; ++v) DST[v] = ez[v];           \
    }                                                                         \
  }
      LDTAP(0, w0)
      LDTAP(1, w1)
      LDTAP(2, w2)
      LDTAP(3, w3)
#undef LDTAP
      char* lb = reinterpret_cast<char*>(lds);
#pragma unroll
      for (int v = 0; v < 9; ++v) {
        uint32_t hi01 = (w0[v] & 0xffffu) | (w1[v] << 16);
        uint32_t hi23 = (w2[v] & 0xffffu) | (w3[v] << 16);
        *reinterpret_cast<uint2*>(lb + v * 2048 + aml * 32 + flq * 8) =
            make_uint2(hi01, hi23);
      }
    }

    // ---- stage B: one plane, 1152 float4s over 256 threads ----
    {
      const unsigned short* bsrc = Bg + (size_t)kc * (9 * COUT * 16);
#define STAGEB(U)                                                             \
  {                                                                           \
    int u = (U);                                                              \
    int v = u >> 7, q = u & 127;                                              \
    int nl = q >> 1, half = q & 1;                                            \
    size_t srcE = (size_t)v * (COUT * 16) + (size_t)(nb * 64 + nl) * 16 +     \
                  half * 8;                                                   \
    int dst = 9216 + v * 1024 + nl * 16 + half * 8;                           \
    *reinterpret_cast<float4*>(&lds[dst]) =                                   \
        *reinterpret_cast<const float4*>(&bsrc[srcE]);                        \
  }
      STAGEB(t)
      STAGEB(256 + t)
      STAGEB(512 + t)
      STAGEB(768 + t)
      if (t < 128) STAGEB(1024 + t)
#undef STAGEB
    }
    __syncthreads();

    // ---- compute: 9 v-steps x 1 product ----
#pragma unroll
    for (int v = 0; v < 9; ++v) {
      const char* lbc = reinterpret_cast<const char*>(lds);
      bf16x8 ah = *reinterpret_cast<const bf16x8*>(lbc + v * 2048 + aoff);
      bf16x8 bh =
          *reinterpret_cast<const bf16x8*>(lbc + 18432 + v * 2048 + boff);
      acc = __builtin_amdgcn_mfma_f32_32x32x16_bf16(ah, bh, acc, 0, 0, 0);
    }
  }

  // ---- epilogue: C/D layout col=lane&31, row=(reg&3)+8*(reg>>2)+4*(lane>>5)
  float* p = part + (size_t)blockIdx.z * M * COUT;
  const int gn = nb * 64 + wn * 32 + frow;
#pragma unroll
  for (int r = 0; r < 16; ++r) {
    int mlocal = (r & 3) + 8 * (r >> 2) + 4 * fkg;
    int gm = mbase + wm * 32 + mlocal;
    p[(size_t)gm * COUT + gn] = acc[r];
  }
}

// ---------------------------------------------------------------------------
// Reduce split-K partials -> activation; write packed 12-stride expansion E.
// ---------------------------------------------------------------------------
template <int COUT, int HO, int WO>
__global__ __launch_bounds__(256) void reduce_pe_pack(
    const float* __restrict__ part, uint32_t* __restrict__ E, int SK) {
  constexpr int M = BATCH * HO * WO;
  int idx = blockIdx.x * 256 + threadIdx.x;
  int ww = idx % WO;
  int tmp = idx / WO;
  int hh = tmp % HO;
  tmp /= HO;
  int o = tmp % COUT;
  int b = tmp / COUT;
  int m = (b * HO + hh) * WO + ww;
  float s = 0.f;
  for (int k = 0; k < SK; ++k) s += part[((size_t)k * M + m) * COUT + o];
  float e[9];
  expand9(s, e);
  uint32_t u0 = packsplit(e[0]), u1 = packsplit(e[1]), u2 = packsplit(e[2]);
  uint32_t u3 = packsplit(e[3]), u4 = packsplit(e[4]), u5 = packsplit(e[5]);
  uint32_t u6 = packsplit(e[6]), u7 = packsplit(e[7]), u8 = packsplit(e[8]);
  uint4* p = reinterpret_cast<uint4*>(E + (size_t)idx * 12);
  p[0] = make_uint4(u0, u1, u2, u3);
  p[1] = make_uint4(u4, u5, u6, u7);
  p[2] = make_uint4(u8, 0u, 0u, 0u);
}

template <int COUT, int HO, int WO>
__global__ __launch_bounds__(256) void reduce_p(
    const float* __restrict__ part, float* __restrict__ act, int SK) {
  constexpr int M = BATCH * HO * WO;
  int idx = blockIdx.x * 256 + threadIdx.x;
  int ww = idx % WO;
  int tmp = idx / WO;
  int hh = tmp % HO;
  tmp /= HO;
  int o = tmp % COUT;
  int b = tmp / COUT;
  int m = (b * HO + hh) * WO + ww;
  float s = 0.f;
  for (int k = 0; k < SK; ++k) s += part[((size_t)k * M + m) * COUT + o];
  act[idx] = s;
}

// ---------------------------------------------------------------------------
// L4 weights, neighbor-pre-summed:
// Wn[c][pc][nb][v][o] = sum over taps mapping to neighbor nb under parity pc.
// ---------------------------------------------------------------------------
__global__ __launch_bounds__(256) void prep_wnl4(
    const float* __restrict__ bw, const float* __restrict__ sw,
    const float* __restrict__ ss, float* __restrict__ Wn) {
  int idx = blockIdx.x * 256 + threadIdx.x;  // 64*4*4*27 = 27648
  if (idx >= 27648) return;
  int u = idx % 27;
  int o = u % 3, v = u / 3;
  int rest = idx / 27;
  int nb = rest & 3;
  rest >>= 2;
  int pc = rest & 3;
  rest >>= 2;
  int c = rest;  // 0..63
  int PH = pc >> 1, PW = pc & 1;
  int a = nb >> 1, b2 = nb & 1;
  float s = 0.f;
#pragma unroll
  for (int kh = 0; kh < 3; ++kh) {
    if (((kh > PH) ? 1 : 0) != a) continue;
#pragma unroll
    for (int kw = 0; kw < 3; ++kw) {
      if (((kw > PW) ? 1 : 0) != b2) continue;
      int f = c * 9 + kh * 3 + kw;
      float wv = (v == 0)
                     ? bw[o * 576 + f]
                     : sw[((size_t)(o * 576 + f)) * 8 + (v - 1)] * ss[o * 576 + f];
      s += wv;
    }
  }
  Wn[idx] = s;
}

// ---------------------------------------------------------------------------
// L4 v8 (round-20 proven): 32 channel groups (2 ch/block, 2048 blocks).
// ---------------------------------------------------------------------------
template <int PH, int PW>
__device__ void l4v8_wave(const float* __restrict__ eLds,
                          const float* __restrict__ WnB,
                          const float* __restrict__ ez, int lane, int bb,
                          int cs, float* __restrict__ p4) {
  constexpr int PC = PH * 2 + PW;
  const int j = lane & 15;
  const int i0 = (lane >> 4) << 2;
#pragma unroll 1
  for (int q = 0; q < 4; ++q) {
    const int i = i0 + q;
    float acc[3] = {0.f, 0.f, 0.f};
#pragma unroll
    for (int a = 0; a < 2; ++a) {
      const int gi = i + PH - 1 + a;
      const bool vr = (unsigned)gi < 16u;
#pragma unroll
      for (int b2 = 0; b2 < 2; ++b2) {
        const int gj = j + PW - 1 + b2;
        const bool ok = vr && ((unsigned)gj < 16u);
        const int pp = ok ? (gi * 16 + gj) : 0;  // clamped safe address
        const int nbi = a * 2 + b2;
#pragma unroll
        for (int cl = 0; cl < 2; ++cl) {
          const float* ep = eLds + cl * 2304 + pp * 9;
          float en[9];
#pragma unroll
          for (int v = 0; v < 9; ++v) en[v] = ok ? ep[v] : ez[v];
          const float* wp = WnB + ((cl * 4 + PC) * 4 + nbi) * 27;
#pragma unroll
          for (int v = 0; v < 9; ++v) {
            acc[0] = fmaf(en[v], wp[v * 3 + 0], acc[0]);
            acc[1] = fmaf(en[v], wp[v * 3 + 1], acc[1]);
            acc[2] = fmaf(en[v], wp[v * 3 + 2], acc[2]);
          }
        }
      }
    }
    const int h = (i << 1) + PH, w = (j << 1) + PW;
#pragma unroll
    for (int o = 0; o < 3; ++o)
      p4[(size_t)cs * 196608 + ((bb * 3 + o) << 10) + (h << 5) + w] = acc[o];
  }
}

__global__ __launch_bounds__(256) void kan_l4_v8(
    const float* __restrict__ a3, const float* __restrict__ Wn,
    float* __restrict__ p4) {
  __shared__ float eLds[2 * 256 * 9];  // 18.4 KB
  const int bid = blockIdx.x;          // 64 bb x 32 cs
  const int bb = bid >> 5, cs = bid & 31;
  const int t = threadIdx.x;
  float ez[9];
  expand9(0.f, ez);
#pragma unroll
  for (int cl = 0; cl < 2; ++cl) {
    float x = a3[(size_t)(bb * 64 + cs * 2 + cl) * 256 + t];
    float ev[9];
    expand9(x, ev);
#pragma unroll
    for (int v = 0; v < 9; ++v) eLds[(cl * 256 + t) * 9 + v] = ev[v];
  }
  __syncthreads();
  const int wv_ = t >> 6, lane = t & 63;
  const float* WnB = Wn + (size_t)cs * 2 * (4 * 4 * 27);
  if (wv_ == 0)
    l4v8_wave<0, 0>(eLds, WnB, ez, lane, bb, cs, p4);
  else if (wv_ == 1)
    l4v8_wave<0, 1>(eLds, WnB, ez, lane, bb, cs, p4);
  else if (wv_ == 2)
    l4v8_wave<1, 0>(eLds, WnB, ez, lane, bb, cs, p4);
  else
    l4v8_wave<1, 1>(eLds, WnB, ez, lane, bb, cs, p4);
}

__global__ __launch_bounds__(256) void reduce_tanh_l4_32(
    const float* __restrict__ p4, float* __restrict__ out) {
  int i = blockIdx.x * 256 + threadIdx.x;  // 196608
  float s = 0.f;
#pragma unroll
  for (int k = 0; k < 32; ++k) s += p4[(size_t)k * 196608 + i];
  out[i] = tanhf(s);
}

__global__ __launch_bounds__(256) void reduce_tanh_l4(
    const float* __restrict__ p4, float* __restrict__ out) {
  int i = blockIdx.x * 256 + threadIdx.x;
  float s = p4[i] + p4[i + 196608] + p4[i + 2 * 196608] + p4[i + 3 * 196608];
  out[i] = tanhf(s);
}

// ---------------------------------------------------------------------------
// Fallback path (round-1 proven) for small workspace
// ---------------------------------------------------------------------------
template <int CIN, int COUT, int HO, int WO, int BN, int SK>
__global__ __launch_bounds__(256) void kan_gemm(
    const float* __restrict__ in, const float* __restrict__ bw,
    const float* __restrict__ sw, const float* __restrict__ ss,
    float* __restrict__ outp) {
  constexpr int BM = 64, TM = 4, TN = 4, FC = 16;
  constexpr int F = CIN * 9;
  constexpr int HI = HO / 2, WI = WO / 2;
  constexpr int M = BATCH * HO * WO;
  constexpr int FPB = F / SK;

  __shared__ float Ae[FC * 9][BM];

  const int t = threadIdx.x;
  const int mbase = blockIdx.x * BM;
  const int obase = blockIdx.y * BN;
  const int f0 = blockIdx.z * FPB;

  const int cg = t & (BN / TN - 1);
  const int rg = t / (BN / TN);
  const int m0 = rg * TM;
  const int o0 = obase + cg * TN;

  float acc[TM][TN] = {};

  for (int fc = f0; fc < f0 + FPB; fc += FC) {
#pragma unroll
    for (int j = 0; j < BM * FC / 256; ++j) {
      int p = j * 256 + t;
      int ml = p & (BM - 1);
      int df = p >> 6;
      int f = fc + df;
      int c = f / 9;
      int r = f - c * 9;
      int kh = r / 3, kw = r - kh * 3;
      int m = mbase + ml;
      int bb = m / (HO * WO);
      int rem = m % (HO * WO);
      int hh = rem / WO, ww = rem % WO;
      int hp = hh + kh - 1, wp = ww + kw - 1;
      float val = 0.f;
      if (hp >= 0 && hp < HO && wp >= 0 && wp < WO)
        val = in[((bb * CIN + c) * HI + (hp >> 1)) * WI + (wp >> 1)];
      float e[9];
      expand9(val, e);
#pragma unroll
      for (int v = 0; v < 9; ++v) Ae[df * 9 + v][ml] = e[v];
    }
    __syncthreads();

#pragma unroll 2
    for (int df = 0; df < FC; ++df) {
      int f = fc + df;
      float wb[TN], wsv[TN][8];
#pragma unroll
      for (int tn = 0; tn < TN; ++tn) {
        int i = (o0 + tn) * F + f;
        wb[tn] = bw[i];
        float sc = ss[i];
        const float4* sp = reinterpret_cast<const float4*>(sw + (size_t)i * 8);
        float4 s0 = sp[0], s1 = sp[1];
        wsv[tn][0] = s0.x * sc; wsv[tn][1] = s0.y * sc;
        wsv[tn][2] = s0.z * sc; wsv[tn][3] = s0.w * sc;
        wsv[tn][4] = s1.x * sc; wsv[tn][5] = s1.y * sc;
        wsv[tn][6] = s1.z * sc; wsv[tn][7] = s1.w * sc;
      }
      float a[9][TM];
#pragma unroll
      for (int v = 0; v < 9; ++v) {
        float4 q = *reinterpret_cast<const float4*>(&Ae[df * 9 + v][m0]);
        a[v][0] = q.x; a[v][1] = q.y; a[v][2] = q.z; a[v][3] = q.w;
      }
#pragma unroll
      for (int tm = 0; tm < TM; ++tm)
#pragma unroll
        for (int tn = 0; tn < TN; ++tn) acc[tm][tn] += a[0][tm] * wb[tn];
#pragma unroll
      for (int v = 1; v < 9; ++v)
#pragma unroll
        for (int tm = 0; tm < TM; ++tm)
#pragma unroll
          for (int tn = 0; tn < TN; ++tn)
            acc[tm][tn] += a[v][tm] * wsv[tn][v - 1];
    }
    __syncthreads();
  }

  if constexpr (SK > 1) {
    float* p = outp + (size_t)blockIdx.z * M * COUT;
#pragma unroll
    for (int tm = 0; tm < TM; ++tm) {
      int m = mbase + m0 + tm;
#pragma unroll
      for (int tn = 0; tn < TN; ++tn)
        p[(size_t)m * COUT + (o0 + tn)] = acc[tm][tn];
    }
  } else {
#pragma unroll
    for (int tm = 0; tm < TM; ++tm) {
      int m = mbase + m0 + tm;
      int bb = m / (HO * WO);
      int rem = m % (HO * WO);
      int hh = rem / WO, ww = rem % WO;
#pragma unroll
      for (int tn = 0; tn < TN; ++tn) {
        int o = o0 + tn;
        outp[((bb * COUT + o) * HO + hh) * WO + ww] = acc[tm][tn];
      }
    }
  }
}

template <int COUT, int HO, int WO, int SK>
__global__ __launch_bounds__(256) void reduce_partials_old(
    const float* __restrict__ part, float* __restrict__ act) {
  constexpr int M = BATCH * HO * WO;
  int idx = blockIdx.x * 256 + threadIdx.x;
  if (idx >= M * COUT) return;
  float s = 0.f;
#pragma unroll
  for (int k = 0; k < SK; ++k) s += part[(size_t)k * M * COUT + idx];
  int m = idx / COUT, o = idx - (idx / COUT) * COUT;
  int bb = m / (HO * WO);
  int rem = m % (HO * WO);
  int hh = rem / WO, ww = rem % WO;
  act[((bb * COUT + o) * HO + hh) * WO + ww] = s;
}

__global__ __launch_bounds__(256) void kan_l4_split(
    const float* __restrict__ a3, const float* __restrict__ bw,
    const float* __restrict__ sw, const float* __restrict__ ss,
    float* __restrict__ p4) {
  int tid = blockIdx.x * 256 + threadIdx.x;
  int cs = tid >> 16, pix = tid & 65535;
  int b = pix >> 10, rem = pix & 1023, h = rem >> 5, w = rem & 31;
  float acc[3] = {0.f, 0.f, 0.f};
  for (int c = cs * 16; c < cs * 16 + 16; ++c) {
#pragma unroll
    for (int kh = 0; kh < 3; ++kh) {
#pragma unroll
      for (int kw = 0; kw < 3; ++kw) {
        int f = (c * 3 + kh) * 3 + kw;
        int hp = h + kh - 1, wp = w + kw - 1;
        float x = 0.f;
        if ((unsigned)hp < 32u && (unsigned)wp < 32u)
          x = a3[((b * 64 + c) * 16 + (hp >> 1)) * 16 + (wp >> 1)];
        float e[9];
        expand9(x, e);
#pragma unroll
        for (int o = 0; o < 3; ++o) {
          int i = o * 576 + f;
          float d = e[1] * sw[i * 8 + 0];
#pragma unroll
          for (int v = 1; v < 8; ++v) d += e[v + 1] * sw[i * 8 + v];
          acc[o] += e[0] * bw[i] + d * ss[i];
        }
      }
    }
  }
#pragma unroll
  for (int o = 0; o < 3; ++o)
    p4[cs * 196608 + ((b * 3 + o) << 10) + (h << 5) + w] = acc[o];
}

// ---------------------------------------------------------------------------
extern "C" void kernel_launch(void* const* d_in, const int* in_sizes, int n_in,
                              void* d_out, int out_size, void* d_ws,
                              size_t ws_size, hipStream_t stream) {
  const float* x     = (const float*)d_in[0];
  const float* lin_w = (const float*)d_in[1];
  const float* lin_b = (const float*)d_in[2];
  const float* bw1 = (const float*)d_in[3];
  const float* sw1 = (const float*)d_in[4];
  const float* ss1 = (const float*)d_in[5];
  const float* bw2 = (const float*)d_in[6];
  const float* sw2 = (const float*)d_in[7];
  const float* ss2 = (const float*)d_in[8];
  const float* bw3 = (const float*)d_in[9];
  const float* sw3 = (const float*)d_in[10];
  const float* ss3 = (const float*)d_in[11];
  const float* bw4 = (const float*)d_in[12];
  const float* sw4 = (const float*)d_in[13];
  const float* ss4 = (const float*)d_in[14];

  float* wsf = (float*)d_ws;
  // ---- main-path layout (round 21 = round 19): 16,973,824 floats = 67.9 MB
  float* h    = wsf;                                       // 131072 (wl4 alias)
  float* a3   = wsf + 131072;                              // 1048576
  unsigned short* Bg = (unsigned short*)(wsf + 1179648);   // 5,308,416 floats
  float* part = wsf + 6488064;                             // 4,194,304 (SK=16)
  uint32_t* Eg = (uint32_t*)(wsf + 10682368);              // 6,291,456 (12/pix)
  float* wl4 = h;
  float* p4  = wsf + 10682368;  // aliases Eg (dead post-L3), 32*196608 floats

  const size_t mainNeed = 16973824ull;

  if (ws_size / 4 >= mainNeed) {
    linear_pack_kernel<<<512, 256, 0, stream>>>(x, lin_w, lin_b, h, Eg, 1);

    // L1: CIN=512 COUT=256 4x4, SK=16 (1024 blocks, CPB=18)
    prep_bpack<4608, 256><<<41472, 256, 0, stream>>>(bw1, sw1, ss1, Bg);
    gemm_mfma<512, 256, 4, 4, 16>
        <<<dim3(16, 4, 16), 256, 0, stream>>>(Eg, Bg, part);
    reduce_pe_pack<256, 4, 4><<<1024, 256, 0, stream>>>(part, Eg, 16);

    // L2: CIN=256 COUT=128 8x8, SK=8 (1024 blocks, CPB=18)
    prep_bpack<2304, 128><<<10368, 256, 0, stream>>>(bw2, sw2, ss2, Bg);
    gemm_mfma<256, 128, 8, 8, 8>
        <<<dim3(64, 2, 8), 256, 0, stream>>>(Eg, Bg, part);
    reduce_pe_pack<128, 8, 8><<<2048, 256, 0, stream>>>(part, Eg, 8);

    // L3: CIN=128 COUT=64 16x16, SK=4 (1024 blocks, CPB=18)
    prep_bpack<1152, 64><<<2592, 256, 0, stream>>>(bw3, sw3, ss3, Bg);
    gemm_mfma<128, 64, 16, 16, 4>
        <<<dim3(256, 1, 4), 256, 0, stream>>>(Eg, Bg, part);
    reduce_p<64, 16, 16><<<4096, 256, 0, stream>>>(part, a3, 4);

    // L4: 32 channel groups (2 ch/block, 2048 blocks) + tanh reduce
    prep_wnl4<<<108, 256, 0, stream>>>(bw4, sw4, ss4, wl4);
    kan_l4_v8<<<2048, 256, 0, stream>>>(a3, wl4, p4);
    reduce_tanh_l4_32<<<768, 256, 0, stream>>>(p4, (float*)d_out);
  } else {
    // round-1 proven fallback (needs ~16.3 MB), original layout
    float* hF  = wsf;
    float* a1F = hF + 131072;
    float* a2F = a1F + 262144;
    float* a3F = a2F + 524288;
    float* partOld = a3F + 1048576;
    linear_pack_kernel<<<512, 256, 0, stream>>>(x, lin_w, lin_b, hF, nullptr, 0);
    kan_gemm<512, 256, 4, 4, 64, 8>
        <<<dim3(16, 4, 8), 256, 0, stream>>>(hF, bw1, sw1, ss1, partOld);
    reduce_partials_old<256, 4, 4, 8><<<1024, 256, 0, stream>>>(partOld, a1F);
    kan_gemm<256, 128, 8, 8, 64, 2>
        <<<dim3(64, 2, 2), 256, 0, stream>>>(a1F, bw2, sw2, ss2, partOld);
    reduce_partials_old<128, 8, 8, 2><<<2048, 256, 0, stream>>>(partOld, a2F);
    kan_gemm<128, 64, 16, 16, 64, 1>
        <<<dim3(256, 1, 1), 256, 0, stream>>>(a2F, bw3, sw3, ss3, a3F);
    kan_l4_split<<<1024, 256, 0, stream>>>(a3F, bw4, sw4, ss4, partOld);
    reduce_tanh_l4<<<768, 256, 0, stream>>>(partOld, (float*)d_out);
  }
}